// Round 1
// baseline (422.408 us; speedup 1.0000x reference)
//
#include <hip/hip_runtime.h>
#include <cstdint>
#include <cstddef>

// Problem constants (fixed shapes from setup_inputs)
namespace {
constexpr int Bn = 8, Dn = 512, Hn = 96, Wn = 96, HWn = Hn * Wn; // 9216
constexpr int Cn = 8, Kn = 10, CKn = Cn * Kn;                    // 80
constexpr float EPSF = 1e-8f;
constexpr float MINM = 0.05f;

// workspace layout (in floats)
constexpr size_t oPnT  = 0;                                   // [D][CK] = 40960
constexpr size_t oS    = oPnT  + (size_t)Dn * CKn;            // [B][HW][K] = 737280
constexpr size_t oNumH = oS    + (size_t)Bn * HWn * Kn;       // [B*C][K][HW] = 5898240
constexpr size_t oDenH = oNumH + (size_t)Bn * Cn * Kn * HWn;  // [B*C][HW] = 589824
constexpr size_t oReg  = oDenH + (size_t)Bn * Cn * HWn;       // [B*C][K][HW] = 5898240
constexpr size_t oDenA = oReg  + (size_t)Bn * Cn * Kn * HWn;  // [B*C][HW] = 589824
constexpr size_t oMean = oDenA + (size_t)Bn * Cn * HWn;       // [B*C][K] = 640 (zeroed)
constexpr size_t oVc   = oMean + (size_t)Bn * Cn * Kn;        // [B*C] float = 64 (zeroed)
constexpr size_t oCnt  = oVc   + 64;                          // [B*C] int = 64 (zeroed)
constexpr size_t oLoss = oCnt  + 64;                          // [B*C] = 64
constexpr size_t oEnd  = oLoss + 64;
} // namespace

__device__ __forceinline__ float wred64(float v) {
#pragma unroll
    for (int o = 32; o > 0; o >>= 1) v += __shfl_down(v, o, 64);
    return v;
}

// ---------------------------------------------------------------------------
// K0: normalize prototypes, store transposed PnT[d][ck]
__global__ __launch_bounds__(64) void k_protonorm(const float* __restrict__ P,
                                                  float* __restrict__ PnT) {
    int ck = blockIdx.x;       // 0..79
    int lane = threadIdx.x;    // 0..63
    float v[8];
    float ss = 0.f;
#pragma unroll
    for (int j = 0; j < 8; ++j) {
        v[j] = P[ck * Dn + lane + 64 * j];
        ss += v[j] * v[j];
    }
    ss = wred64(ss);
    ss = __shfl(ss, 0, 64);
    float inv = 1.0f / fmaxf(sqrtf(ss), 1e-12f);
#pragma unroll
    for (int j = 0; j < 8; ++j)
        PnT[(size_t)(lane + 64 * j) * CKn + ck] = v[j] * inv;
}

// ---------------------------------------------------------------------------
// K1: per-pixel sim with own-class prototypes: S[b][hw][k] = <Fn, Pn[c,k]>,
//     0 if mask==0. Also per-(b,c) pixel count histogram.
__global__ __launch_bounds__(256) void k_sim(const float* __restrict__ F,
                                             const float* __restrict__ PnT,
                                             const int* __restrict__ mask,
                                             float* __restrict__ S,
                                             int* __restrict__ cnt) {
    __shared__ float pch[64 * CKn]; // 20 KB: [dd][ck]
    __shared__ int hist[Cn];
    const int tid = threadIdx.x;
    const int blk = blockIdx.x;            // B*HW/256 = 2304 blocks
    const int b = blk / (HWn / 256);
    const int hw = (blk % (HWn / 256)) * 256 + tid;

    if (tid < Cn) hist[tid] = 0;

    const int m = mask[b * HWn + hw];
    const int c = m - 1;                   // -1..7
    const int cc = c < 0 ? 0 : c;

    float acc[Kn];
#pragma unroll
    for (int k = 0; k < Kn; ++k) acc[k] = 0.f;
    float ss = 0.f;

    for (int d0 = 0; d0 < Dn; d0 += 64) {
        __syncthreads();
        // stage PnT[d0..d0+63][*] -> pch (contiguous, coalesced)
        for (int i = tid; i < 64 * CKn; i += 256)
            pch[i] = PnT[(size_t)d0 * CKn + i];
        __syncthreads();
#pragma unroll 4
        for (int dd = 0; dd < 64; ++dd) {
            float f = F[(size_t)(b * Dn + d0 + dd) * HWn + hw];
            ss += f * f;
            const float* pr = &pch[dd * CKn + cc * Kn];
#pragma unroll
            for (int k = 0; k < Kn; ++k) acc[k] += f * pr[k];
        }
    }
    float inv = 1.0f / fmaxf(sqrtf(ss), 1e-12f);
    const bool has = (c >= 0);
    float* Sp = &S[((size_t)b * HWn + hw) * Kn];
#pragma unroll
    for (int k = 0; k < Kn; ++k) Sp[k] = has ? acc[k] * inv : 0.f;

    if (has) atomicAdd(&hist[c], 1);
    __syncthreads();
    if (tid < Cn) atomicAdd(&cnt[b * Cn + tid], hist[tid]);
}

// ---------------------------------------------------------------------------
// K2: horizontal 7-wide pooling per class.
__global__ __launch_bounds__(256) void k_hpool(const int* __restrict__ mask,
                                               const float* __restrict__ S,
                                               float* __restrict__ numH,
                                               float* __restrict__ denH) {
    const int i = blockIdx.x * 256 + threadIdx.x; // (b,c,hw), hw fastest
    const int hw = i % HWn;
    const int bc = i / HWn;
    const int c = bc % Cn;
    const int b = bc / Cn;
    const int w = hw % Wn;
    const int row = hw - w; // h*96

    float den = 0.f;
    float acc[Kn];
#pragma unroll
    for (int k = 0; k < Kn; ++k) acc[k] = 0.f;

#pragma unroll
    for (int dx = -3; dx <= 3; ++dx) {
        int ww = w + dx;
        if (ww < 0 || ww >= Wn) continue;
        int px = b * HWn + row + ww;
        if (mask[px] == c + 1) {
            den += 1.0f;
            const float* Sp = &S[(size_t)px * Kn];
#pragma unroll
            for (int k = 0; k < Kn; ++k) acc[k] += Sp[k];
        }
    }
    denH[i] = den;
#pragma unroll
    for (int k = 0; k < Kn; ++k)
        numH[(size_t)(bc * Kn + k) * HWn + hw] = acc[k];
}

// ---------------------------------------------------------------------------
// K3: vertical 7-wide pooling -> region, den_avg; fused partial sums for
//     per-(b,c) mean and valid count (block spans single bc).
__global__ __launch_bounds__(256) void k_vpool(const float* __restrict__ numH,
                                               const float* __restrict__ denH,
                                               float* __restrict__ region,
                                               float* __restrict__ denA,
                                               float* __restrict__ meanSum,
                                               float* __restrict__ Vcnt) {
    const int i = blockIdx.x * 256 + threadIdx.x;
    const int hw = i % HWn;
    const int bc = i / HWn;
    const int w = hw % Wn;
    const int h = hw / Wn;

    float den = 0.f;
    float num[Kn];
#pragma unroll
    for (int k = 0; k < Kn; ++k) num[k] = 0.f;

#pragma unroll
    for (int dy = -3; dy <= 3; ++dy) {
        int hh = h + dy;
        if (hh < 0 || hh >= Hn) continue;
        int j = bc * HWn + hh * Wn + w;
        den += denH[j];
#pragma unroll
        for (int k = 0; k < Kn; ++k)
            num[k] += numH[(size_t)(bc * Kn + k) * HWn + hh * Wn + w];
    }
    float dA = den / 49.0f;
    bool valid = dA > MINM;
    float vm = valid ? 1.0f : 0.0f;
    float rv[Kn];
#pragma unroll
    for (int k = 0; k < Kn; ++k) {
        rv[k] = (num[k] / 49.0f) / (dA + EPSF);
        region[(size_t)(bc * Kn + k) * HWn + hw] = rv[k];
    }
    denA[i] = dA;

    // block reduce 11 quantities: [count, rv[0..9]*vm]
    __shared__ float red[4][11];
    const int lane = threadIdx.x & 63;
    const int wv = threadIdx.x >> 6;
    float vals[11];
    vals[0] = vm;
#pragma unroll
    for (int k = 0; k < Kn; ++k) vals[k + 1] = rv[k] * vm;
#pragma unroll
    for (int t = 0; t < 11; ++t) {
        float r = wred64(vals[t]);
        if (lane == 0) red[wv][t] = r;
    }
    __syncthreads();
    if (threadIdx.x < 11) {
        float s = red[0][threadIdx.x] + red[1][threadIdx.x] +
                  red[2][threadIdx.x] + red[3][threadIdx.x];
        if (threadIdx.x == 0) atomicAdd(&Vcnt[bc], s);
        else                  atomicAdd(&meanSum[bc * Kn + threadIdx.x - 1], s);
    }
}

// ---------------------------------------------------------------------------
// K4: per-(b,c) centered cross-products -> gram -> loss_c
__global__ __launch_bounds__(256) void k_gram(const float* __restrict__ region,
                                              const float* __restrict__ denA,
                                              const float* __restrict__ meanSum,
                                              const float* __restrict__ Vcnt,
                                              float* __restrict__ lossc) {
    const int bc = blockIdx.x;
    const float cntf = Vcnt[bc];
    const float Vf = fmaxf(cntf, 1.0f);
    float mean[Kn];
#pragma unroll
    for (int k = 0; k < Kn; ++k) mean[k] = meanSum[bc * Kn + k] / Vf;

    float M[55];
#pragma unroll
    for (int t = 0; t < 55; ++t) M[t] = 0.f;

    for (int i = threadIdx.x; i < HWn; i += 256) {
        if (denA[bc * HWn + i] > MINM) {
            float a[Kn];
#pragma unroll
            for (int k = 0; k < Kn; ++k)
                a[k] = region[(size_t)(bc * Kn + k) * HWn + i] - mean[k];
            int p = 0;
#pragma unroll
            for (int k = 0; k < Kn; ++k)
#pragma unroll
                for (int l = 0; l <= k; ++l, ++p) M[p] += a[k] * a[l];
        }
    }

    __shared__ float red[4][55];
    const int lane = threadIdx.x & 63;
    const int wv = threadIdx.x >> 6;
#pragma unroll
    for (int t = 0; t < 55; ++t) {
        float r = wred64(M[t]);
        if (lane == 0) red[wv][t] = r;
    }
    __syncthreads();
    if (threadIdx.x == 0) {
        float Mm[55];
#pragma unroll
        for (int t = 0; t < 55; ++t)
            Mm[t] = red[0][t] + red[1][t] + red[2][t] + red[3][t];
        float nrm[Kn];
#pragma unroll
        for (int k = 0; k < Kn; ++k) nrm[k] = sqrtf(Mm[k * (k + 1) / 2 + k]);
        float loss = 0.f;
        int p = 0;
#pragma unroll
        for (int k = 0; k < Kn; ++k) {
#pragma unroll
            for (int l = 0; l <= k; ++l, ++p) {
                if (l == k) continue;
                float g = Mm[p] / ((nrm[k] + EPSF) * (nrm[l] + EPSF)) / Vf;
                loss += 2.0f * g * g;
            }
        }
        lossc[bc] = loss / (float)(Kn * (Kn - 1));
    }
}

// ---------------------------------------------------------------------------
// K5: active mask, per-image average, final scalar
__global__ __launch_bounds__(64) void k_final(const float* __restrict__ lossc,
                                              const float* __restrict__ Vcnt,
                                              const int* __restrict__ cnt,
                                              float* __restrict__ out) {
    if (threadIdx.x == 0 && blockIdx.x == 0) {
        float tot = 0.f;
        for (int b = 0; b < Bn; ++b) {
            float sa = 0.f, sl = 0.f;
            for (int c = 0; c < Cn; ++c) {
                int bc = b * Cn + c;
                bool act = (cnt[bc] >= 1) && (Vcnt[bc] >= 2.0f);
                if (act) { sa += 1.0f; sl += lossc[bc]; }
            }
            tot += sl / fmaxf(sa, 1.0f);
        }
        out[0] = tot / (float)Bn;
    }
}

// ---------------------------------------------------------------------------
extern "C" void kernel_launch(void* const* d_in, const int* in_sizes, int n_in,
                              void* d_out, int out_size, void* d_ws, size_t ws_size,
                              hipStream_t stream) {
    const float* F   = (const float*)d_in[0]; // [8,512,96,96]
    const float* P   = (const float*)d_in[1]; // [80,512]
    const int* mask  = (const int*)d_in[2];   // [8,96,96]
    float* ws = (float*)d_ws;
    float* out = (float*)d_out;

    // zero the atomic-accumulator zone (meanSum, Vcnt, cnt, lossc)
    hipMemsetAsync(ws + oMean, 0, (oEnd - oMean) * sizeof(float), stream);

    k_protonorm<<<CKn, 64, 0, stream>>>(P, ws + oPnT);
    k_sim<<<Bn * HWn / 256, 256, 0, stream>>>(F, ws + oPnT, mask, ws + oS,
                                              (int*)(ws + oCnt));
    k_hpool<<<Bn * Cn * HWn / 256, 256, 0, stream>>>(mask, ws + oS,
                                                     ws + oNumH, ws + oDenH);
    k_vpool<<<Bn * Cn * HWn / 256, 256, 0, stream>>>(ws + oNumH, ws + oDenH,
                                                     ws + oReg, ws + oDenA,
                                                     ws + oMean, ws + oVc);
    k_gram<<<Bn * Cn, 256, 0, stream>>>(ws + oReg, ws + oDenA, ws + oMean,
                                        ws + oVc, ws + oLoss);
    k_final<<<1, 64, 0, stream>>>(ws + oLoss, ws + oVc,
                                  (const int*)(ws + oCnt), out);
}

// Round 2
// 356.999 us; speedup vs baseline: 1.1832x; 1.1832x over previous
//
#include <hip/hip_runtime.h>
#include <cstdint>
#include <cstddef>

namespace {
constexpr int Bn = 8, Dn = 512, Hn = 96, Wn = 96, HWn = Hn * Wn; // 9216
constexpr int Cn = 8, Kn = 10, CKn = Cn * Kn;                    // 80
constexpr int NPIX = Bn * HWn;                                   // 73728
constexpr int NCHUNK = 4, DCH = Dn / NCHUNK;                     // 4 x 128
constexpr float EPSF = 1e-8f;
constexpr float MINM = 0.05f;

// workspace layout (floats)
constexpr size_t oPnT  = 0;                                    // [D][CK] 40960
constexpr size_t oS    = oPnT + (size_t)Dn * CKn;              // [B][K][HW] 737280
constexpr size_t oNumH = oS + (size_t)Bn * Kn * HWn;           // [BC][K][HW] 5898240
constexpr size_t oPart = oNumH;                                // alias: [chunk][11][NPIX] = 3244032 (consumed before numH written)
constexpr size_t oDenH = oNumH + (size_t)Bn * Cn * Kn * HWn;   // [BC][HW] 589824
constexpr size_t oReg  = oDenH + (size_t)Bn * Cn * HWn;        // [BC][K][HW] 5898240
constexpr size_t oDenA = oReg + (size_t)Bn * Cn * Kn * HWn;    // [BC][HW] 589824
constexpr size_t oMean = oDenA + (size_t)Bn * Cn * HWn;        // [BC][K] 640   (zeroed)
constexpr size_t oVc   = oMean + 640;                          // [BC] 64      (zeroed)
constexpr size_t oCnt  = oVc + 64;                             // [BC] int 64  (zeroed)
constexpr size_t oMws  = oCnt + 64;                            // [BC][55] 3520 (zeroed)
constexpr size_t oEnd  = oMws + 64 * 55;
} // namespace

__device__ __forceinline__ float wred64(float v) {
#pragma unroll
    for (int o = 32; o > 0; o >>= 1) v += __shfl_down(v, o, 64);
    return v;
}

// ---------------------------------------------------------------------------
// K0: normalize prototypes, store transposed PnT[d][ck]
__global__ __launch_bounds__(64) void k_protonorm(const float* __restrict__ P,
                                                  float* __restrict__ PnT) {
    int ck = blockIdx.x, lane = threadIdx.x;
    float v[8]; float ss = 0.f;
#pragma unroll
    for (int j = 0; j < 8; ++j) { v[j] = P[ck * Dn + lane + 64 * j]; ss += v[j] * v[j]; }
    ss = wred64(ss);
    ss = __shfl(ss, 0, 64);
    float inv = 1.0f / fmaxf(sqrtf(ss), 1e-12f);
#pragma unroll
    for (int j = 0; j < 8; ++j)
        PnT[(size_t)(lane + 64 * j) * CKn + ck] = v[j] * inv;
}

// ---------------------------------------------------------------------------
// K1: split-D partial sims. grid (288 pixel-blocks, 4 d-chunks).
// part[(chunk*11 + j)*NPIX + pixel]: j=0..9 acc_k, j=10 ss
__global__ __launch_bounds__(256) void k_sim(const float* __restrict__ F,
                                             const float* __restrict__ PnT,
                                             const int* __restrict__ mask,
                                             float* __restrict__ part) {
    __shared__ float pch[64 * 96]; // [dd][c*12+k], padded, 24.6 KB
    const int tid = threadIdx.x;
    const int pix = blockIdx.x * 256 + tid;     // = b*HWn + hw (b-major)
    const int chunk = blockIdx.y;
    const int b = pix / HWn, hw = pix % HWn;

    const int m = mask[pix];
    const int cc = m > 0 ? m - 1 : 0;

    float acc[Kn]; float ss = 0.f;
#pragma unroll
    for (int k = 0; k < Kn; ++k) acc[k] = 0.f;

    for (int p = 0; p < DCH / 64; ++p) {
        const int dbase = chunk * DCH + p * 64;
        __syncthreads();
        for (int i = tid; i < 64 * CKn; i += 256) {
            int dd = i / CKn, ck = i % CKn;
            int c = ck / Kn, kk = ck % Kn;
            pch[dd * 96 + c * 12 + kk] = PnT[(size_t)(dbase + dd) * CKn + ck];
        }
        __syncthreads();
#pragma unroll 4
        for (int dd = 0; dd < 64; ++dd) {
            float f = F[(size_t)(b * Dn + dbase + dd) * HWn + hw];
            ss += f * f;
            const float4* p4 = (const float4*)&pch[dd * 96 + cc * 12];
            float4 pa = p4[0], pb = p4[1];
            float2 pc = *(const float2*)&pch[dd * 96 + cc * 12 + 8];
            acc[0] += f * pa.x; acc[1] += f * pa.y; acc[2] += f * pa.z; acc[3] += f * pa.w;
            acc[4] += f * pb.x; acc[5] += f * pb.y; acc[6] += f * pb.z; acc[7] += f * pb.w;
            acc[8] += f * pc.x; acc[9] += f * pc.y;
        }
    }
#pragma unroll
    for (int k = 0; k < Kn; ++k)
        part[(size_t)(chunk * 11 + k) * NPIX + pix] = acc[k];
    part[(size_t)(chunk * 11 + 10) * NPIX + pix] = ss;
}

// ---------------------------------------------------------------------------
// K2: reduce chunks, normalize, write S[b][k][hw]; class histogram.
__global__ __launch_bounds__(256) void k_simred(const float* __restrict__ part,
                                                const int* __restrict__ mask,
                                                float* __restrict__ S,
                                                int* __restrict__ cnt) {
    __shared__ int hist[Cn];
    const int tid = threadIdx.x;
    const int pix = blockIdx.x * 256 + tid;
    if (tid < Cn) hist[tid] = 0;
    __syncthreads();

    float acc[Kn]; float ss = 0.f;
#pragma unroll
    for (int k = 0; k < Kn; ++k) acc[k] = 0.f;
#pragma unroll
    for (int ch = 0; ch < NCHUNK; ++ch) {
#pragma unroll
        for (int k = 0; k < Kn; ++k)
            acc[k] += part[(size_t)(ch * 11 + k) * NPIX + pix];
        ss += part[(size_t)(ch * 11 + 10) * NPIX + pix];
    }
    float inv = 1.0f / fmaxf(sqrtf(ss), 1e-12f);
    const int b = pix / HWn, hw = pix % HWn;
#pragma unroll
    for (int k = 0; k < Kn; ++k)
        S[(size_t)(b * Kn + k) * HWn + hw] = acc[k] * inv;

    const int m = mask[pix];
    if (m > 0) atomicAdd(&hist[m - 1], 1);
    __syncthreads();
    if (tid < Cn) atomicAdd(&cnt[(pix / HWn) * Cn + tid], hist[tid]);
}

// ---------------------------------------------------------------------------
// K3: horizontal 7-pool; thread per (bc, k-pair, hw)
__global__ __launch_bounds__(256) void k_hpool(const int* __restrict__ mask,
                                               const float* __restrict__ S,
                                               float* __restrict__ numH,
                                               float* __restrict__ denH) {
    const int i = blockIdx.x * 256 + threadIdx.x;
    const int hw = i % HWn;
    const int t = i / HWn;
    const int k2 = t % 5, bc = t / 5;
    const int c = bc % Cn, b = bc / Cn;
    const int k0 = 2 * k2;
    const int w = hw % Wn, row = hw - w;

    float den = 0.f, a0 = 0.f, a1 = 0.f;
#pragma unroll
    for (int dx = -3; dx <= 3; ++dx) {
        int ww = w + dx;
        if (ww < 0 || ww >= Wn) continue;
        int px = row + ww;
        bool hit = (mask[b * HWn + px] == c + 1);
        float s0 = S[(size_t)(b * Kn + k0) * HWn + px];
        float s1 = S[(size_t)(b * Kn + k0 + 1) * HWn + px];
        if (hit) { den += 1.f; a0 += s0; a1 += s1; }
    }
    numH[(size_t)(bc * Kn + k0) * HWn + hw] = a0;
    numH[(size_t)(bc * Kn + k0 + 1) * HWn + hw] = a1;
    if (k2 == 0) denH[(size_t)bc * HWn + hw] = den;
}

// ---------------------------------------------------------------------------
// K4: vertical 7-pool -> region/denA + fused mean/V partial reduction
__global__ __launch_bounds__(256) void k_vpool(const float* __restrict__ numH,
                                               const float* __restrict__ denH,
                                               float* __restrict__ region,
                                               float* __restrict__ denA,
                                               float* __restrict__ meanSum,
                                               float* __restrict__ Vcnt) {
    const int i = blockIdx.x * 256 + threadIdx.x;
    const int hw = i % HWn;
    const int t = i / HWn;
    const int k2 = t % 5, bc = t / 5;
    const int k0 = 2 * k2;
    const int w = hw % Wn, h = hw / Wn;

    float den = 0.f, n0 = 0.f, n1 = 0.f;
#pragma unroll
    for (int dy = -3; dy <= 3; ++dy) {
        int hh = h + dy;
        if (hh < 0 || hh >= Hn) continue;
        int px = hh * Wn + w;
        den += denH[(size_t)bc * HWn + px];
        n0 += numH[(size_t)(bc * Kn + k0) * HWn + px];
        n1 += numH[(size_t)(bc * Kn + k0 + 1) * HWn + px];
    }
    float dA = den * (1.0f / 49.0f);
    float r0 = (n0 * (1.0f / 49.0f)) / (dA + EPSF);
    float r1 = (n1 * (1.0f / 49.0f)) / (dA + EPSF);
    region[(size_t)(bc * Kn + k0) * HWn + hw] = r0;
    region[(size_t)(bc * Kn + k0 + 1) * HWn + hw] = r1;
    if (k2 == 0) denA[(size_t)bc * HWn + hw] = dA;

    float vm = (dA > MINM) ? 1.0f : 0.0f;
    __shared__ float red[4][3];
    const int lane = threadIdx.x & 63, wv = threadIdx.x >> 6;
    float v0 = wred64(vm);
    float v1 = wred64(r0 * vm);
    float v2 = wred64(r1 * vm);
    if (lane == 0) { red[wv][0] = v0; red[wv][1] = v1; red[wv][2] = v2; }
    __syncthreads();
    if (threadIdx.x == 0) {
        float s0 = red[0][0] + red[1][0] + red[2][0] + red[3][0];
        float s1 = red[0][1] + red[1][1] + red[2][1] + red[3][1];
        float s2 = red[0][2] + red[1][2] + red[2][2] + red[3][2];
        atomicAdd(&meanSum[bc * Kn + k0], s1);
        atomicAdd(&meanSum[bc * Kn + k0 + 1], s2);
        if (k2 == 0) atomicAdd(&Vcnt[bc], s0);
    }
}

// ---------------------------------------------------------------------------
// K5: partial centered gram; grid (bc, 8 hw-splits) -> atomic M[55]
__global__ __launch_bounds__(256) void k_gram(const float* __restrict__ region,
                                              const float* __restrict__ denA,
                                              const float* __restrict__ meanSum,
                                              const float* __restrict__ Vcnt,
                                              float* __restrict__ Mws) {
    const int bc = blockIdx.x / 8, s = blockIdx.x % 8;
    const float Vf = fmaxf(Vcnt[bc], 1.0f);
    float mean[Kn];
#pragma unroll
    for (int k = 0; k < Kn; ++k) mean[k] = meanSum[bc * Kn + k] / Vf;

    float M[55];
#pragma unroll
    for (int t = 0; t < 55; ++t) M[t] = 0.f;

    const int lim = (s + 1) * (HWn / 8);
    for (int i = s * (HWn / 8) + threadIdx.x; i < lim; i += 256) {
        if (denA[(size_t)bc * HWn + i] > MINM) {
            float a[Kn];
#pragma unroll
            for (int k = 0; k < Kn; ++k)
                a[k] = region[(size_t)(bc * Kn + k) * HWn + i] - mean[k];
            int p = 0;
#pragma unroll
            for (int k = 0; k < Kn; ++k)
#pragma unroll
                for (int l = 0; l <= k; ++l, ++p) M[p] += a[k] * a[l];
        }
    }
    __shared__ float red[4][55];
    const int lane = threadIdx.x & 63, wv = threadIdx.x >> 6;
#pragma unroll
    for (int t = 0; t < 55; ++t) {
        float r = wred64(M[t]);
        if (lane == 0) red[wv][t] = r;
    }
    __syncthreads();
    for (int t = threadIdx.x; t < 55; t += 256)
        atomicAdd(&Mws[bc * 55 + t], red[0][t] + red[1][t] + red[2][t] + red[3][t]);
}

// ---------------------------------------------------------------------------
// K6: finalize: loss_c per bc (one lane each), active mask, scalar out
__global__ __launch_bounds__(64) void k_final(const float* __restrict__ Mws,
                                              const float* __restrict__ Vcnt,
                                              const int* __restrict__ cnt,
                                              float* __restrict__ out) {
    const int bc = threadIdx.x; // 0..63
    float Mm[55];
#pragma unroll
    for (int t = 0; t < 55; ++t) Mm[t] = Mws[bc * 55 + t];
    const float cf = Vcnt[bc];
    const float Vf = fmaxf(cf, 1.0f);
    float nrm[Kn];
#pragma unroll
    for (int k = 0; k < Kn; ++k) nrm[k] = sqrtf(Mm[k * (k + 1) / 2 + k]);
    float loss = 0.f;
    int p = 0;
#pragma unroll
    for (int k = 0; k < Kn; ++k) {
#pragma unroll
        for (int l = 0; l <= k; ++l, ++p) {
            if (l == k) continue;
            float g = Mm[p] / ((nrm[k] + EPSF) * (nrm[l] + EPSF)) / Vf;
            loss += 2.0f * g * g;
        }
    }
    loss *= 1.0f / (float)(Kn * (Kn - 1));
    bool act = (cnt[bc] >= 1) && (cf >= 2.0f);
    float sl = act ? loss : 0.f;
    float sa = act ? 1.f : 0.f;
#pragma unroll
    for (int o = 4; o > 0; o >>= 1) {
        sl += __shfl_down(sl, o, 8);
        sa += __shfl_down(sa, o, 8);
    }
    __shared__ float pimg[Bn];
    if ((bc & 7) == 0) pimg[bc >> 3] = sl / fmaxf(sa, 1.0f);
    __syncthreads();
    if (bc == 0) {
        float tot = 0.f;
#pragma unroll
        for (int b = 0; b < Bn; ++b) tot += pimg[b];
        out[0] = tot / (float)Bn;
    }
}

// ---------------------------------------------------------------------------
extern "C" void kernel_launch(void* const* d_in, const int* in_sizes, int n_in,
                              void* d_out, int out_size, void* d_ws, size_t ws_size,
                              hipStream_t stream) {
    const float* F  = (const float*)d_in[0];
    const float* P  = (const float*)d_in[1];
    const int* mask = (const int*)d_in[2];
    float* ws = (float*)d_ws;
    float* out = (float*)d_out;

    hipMemsetAsync(ws + oMean, 0, (oEnd - oMean) * sizeof(float), stream);

    k_protonorm<<<CKn, 64, 0, stream>>>(P, ws + oPnT);
    k_sim<<<dim3(NPIX / 256, NCHUNK), 256, 0, stream>>>(F, ws + oPnT, mask, ws + oPart);
    k_simred<<<NPIX / 256, 256, 0, stream>>>(ws + oPart, mask, ws + oS, (int*)(ws + oCnt));
    k_hpool<<<Bn * Cn * 5 * HWn / 256, 256, 0, stream>>>(mask, ws + oS, ws + oNumH, ws + oDenH);
    k_vpool<<<Bn * Cn * 5 * HWn / 256, 256, 0, stream>>>(ws + oNumH, ws + oDenH,
                                                         ws + oReg, ws + oDenA,
                                                         ws + oMean, ws + oVc);
    k_gram<<<Bn * Cn * 8, 256, 0, stream>>>(ws + oReg, ws + oDenA, ws + oMean,
                                            ws + oVc, ws + oMws);
    k_final<<<1, 64, 0, stream>>>(ws + oMws, ws + oVc, (const int*)(ws + oCnt), out);
}

// Round 3
// 308.351 us; speedup vs baseline: 1.3699x; 1.1578x over previous
//
#include <hip/hip_runtime.h>
#include <cstdint>
#include <cstddef>

namespace {
constexpr int Bn = 8, Dn = 512, Hn = 96, Wn = 96, HWn = Hn * Wn; // 9216
constexpr int Cn = 8, Kn = 10, CKn = Cn * Kn;                    // 80
constexpr int NPIX = Bn * HWn;                                   // 73728
constexpr int NCHUNK = 4, DCH = Dn / NCHUNK;                     // 4 x 128
constexpr int NMOM = 66;                                         // vm, 10 S_k, 55 S_kl
constexpr float EPSF = 1e-8f;
constexpr float MINM = 0.05f;

// workspace layout (floats)
constexpr size_t oPnT  = 0;                                    // [D][CK] 40960
constexpr size_t oS    = oPnT + (size_t)Dn * CKn;              // [B][K][HW] 737280
constexpr size_t oNumH = oS + (size_t)Bn * Kn * HWn;           // [BC][K][HW] 5898240
constexpr size_t oPart = oNumH;                                // alias: [chunk][11][NPIX] = 3244032 (consumed before numH written)
constexpr size_t oDenH = oNumH + (size_t)Bn * Cn * Kn * HWn;   // [BC][HW] 589824
constexpr size_t oMom  = oDenH + (size_t)Bn * Cn * HWn;        // [BC][66] 4224 (zeroed)
constexpr size_t oCnt  = oMom + 64 * NMOM;                     // [BC] int 64  (zeroed)
constexpr size_t oEnd  = oCnt + 64;
} // namespace

__device__ __forceinline__ float wred64(float v) {
#pragma unroll
    for (int o = 32; o > 0; o >>= 1) v += __shfl_down(v, o, 64);
    return v;
}

// ---------------------------------------------------------------------------
// K0: normalize prototypes, store transposed PnT[d][ck]
__global__ __launch_bounds__(64) void k_protonorm(const float* __restrict__ P,
                                                  float* __restrict__ PnT) {
    int ck = blockIdx.x, lane = threadIdx.x;
    float v[8]; float ss = 0.f;
#pragma unroll
    for (int j = 0; j < 8; ++j) { v[j] = P[ck * Dn + lane + 64 * j]; ss += v[j] * v[j]; }
    ss = wred64(ss);
    ss = __shfl(ss, 0, 64);
    float inv = 1.0f / fmaxf(sqrtf(ss), 1e-12f);
#pragma unroll
    for (int j = 0; j < 8; ++j)
        PnT[(size_t)(lane + 64 * j) * CKn + ck] = v[j] * inv;
}

// ---------------------------------------------------------------------------
// K1: split-D partial sims. grid (288 pixel-blocks, 4 d-chunks).
__global__ __launch_bounds__(256) void k_sim(const float* __restrict__ F,
                                             const float* __restrict__ PnT,
                                             const int* __restrict__ mask,
                                             float* __restrict__ part) {
    __shared__ float pch[64 * 96]; // [dd][c*12+k], padded, 24.6 KB
    const int tid = threadIdx.x;
    const int pix = blockIdx.x * 256 + tid;
    const int chunk = blockIdx.y;
    const int b = pix / HWn, hw = pix % HWn;

    const int m = mask[pix];
    const int cc = m > 0 ? m - 1 : 0;

    float acc[Kn]; float ss = 0.f;
#pragma unroll
    for (int k = 0; k < Kn; ++k) acc[k] = 0.f;

    for (int p = 0; p < DCH / 64; ++p) {
        const int dbase = chunk * DCH + p * 64;
        __syncthreads();
        for (int i = tid; i < 64 * CKn; i += 256) {
            int dd = i / CKn, ck = i % CKn;
            int c = ck / Kn, kk = ck % Kn;
            pch[dd * 96 + c * 12 + kk] = PnT[(size_t)(dbase + dd) * CKn + ck];
        }
        __syncthreads();
#pragma unroll 4
        for (int dd = 0; dd < 64; ++dd) {
            float f = F[(size_t)(b * Dn + dbase + dd) * HWn + hw];
            ss += f * f;
            const float4* p4 = (const float4*)&pch[dd * 96 + cc * 12];
            float4 pa = p4[0], pb = p4[1];
            float2 pc = *(const float2*)&pch[dd * 96 + cc * 12 + 8];
            acc[0] += f * pa.x; acc[1] += f * pa.y; acc[2] += f * pa.z; acc[3] += f * pa.w;
            acc[4] += f * pb.x; acc[5] += f * pb.y; acc[6] += f * pb.z; acc[7] += f * pb.w;
            acc[8] += f * pc.x; acc[9] += f * pc.y;
        }
    }
#pragma unroll
    for (int k = 0; k < Kn; ++k)
        part[(size_t)(chunk * 11 + k) * NPIX + pix] = acc[k];
    part[(size_t)(chunk * 11 + 10) * NPIX + pix] = ss;
}

// ---------------------------------------------------------------------------
// K2: reduce chunks, normalize, write S[b][k][hw]; class histogram.
__global__ __launch_bounds__(256) void k_simred(const float* __restrict__ part,
                                                const int* __restrict__ mask,
                                                float* __restrict__ S,
                                                int* __restrict__ cnt) {
    __shared__ int hist[Cn];
    const int tid = threadIdx.x;
    const int pix = blockIdx.x * 256 + tid;
    if (tid < Cn) hist[tid] = 0;
    __syncthreads();

    float acc[Kn]; float ss = 0.f;
#pragma unroll
    for (int k = 0; k < Kn; ++k) acc[k] = 0.f;
#pragma unroll
    for (int ch = 0; ch < NCHUNK; ++ch) {
#pragma unroll
        for (int k = 0; k < Kn; ++k)
            acc[k] += part[(size_t)(ch * 11 + k) * NPIX + pix];
        ss += part[(size_t)(ch * 11 + 10) * NPIX + pix];
    }
    float inv = 1.0f / fmaxf(sqrtf(ss), 1e-12f);
    const int b = pix / HWn, hw = pix % HWn;
#pragma unroll
    for (int k = 0; k < Kn; ++k)
        S[(size_t)(b * Kn + k) * HWn + hw] = acc[k] * inv;

    const int m = mask[pix];
    if (m > 0) atomicAdd(&hist[m - 1], 1);
    __syncthreads();
    if (tid < Cn) atomicAdd(&cnt[(pix / HWn) * Cn + tid], hist[tid]);
}

// ---------------------------------------------------------------------------
// K3: horizontal 7-pool; thread per (bc, k-pair, hw)
__global__ __launch_bounds__(256) void k_hpool(const int* __restrict__ mask,
                                               const float* __restrict__ S,
                                               float* __restrict__ numH,
                                               float* __restrict__ denH) {
    const int i = blockIdx.x * 256 + threadIdx.x;
    const int hw = i % HWn;
    const int t = i / HWn;
    const int k2 = t % 5, bc = t / 5;
    const int c = bc % Cn, b = bc / Cn;
    const int k0 = 2 * k2;
    const int w = hw % Wn, row = hw - w;

    float den = 0.f, a0 = 0.f, a1 = 0.f;
#pragma unroll
    for (int dx = -3; dx <= 3; ++dx) {
        int ww = w + dx;
        if (ww < 0 || ww >= Wn) continue;
        int px = row + ww;
        bool hit = (mask[b * HWn + px] == c + 1);
        float s0 = S[(size_t)(b * Kn + k0) * HWn + px];
        float s1 = S[(size_t)(b * Kn + k0 + 1) * HWn + px];
        if (hit) { den += 1.f; a0 += s0; a1 += s1; }
    }
    numH[(size_t)(bc * Kn + k0) * HWn + hw] = a0;
    numH[(size_t)(bc * Kn + k0 + 1) * HWn + hw] = a1;
    if (k2 == 0) denH[(size_t)bc * HWn + hw] = den;
}

// ---------------------------------------------------------------------------
// K4: vertical 7-pool -> region values in registers -> fused raw-moment
// reduction (vm, S_k, S_kl). Blocks stay within one bc (9216/256=36).
__global__ __launch_bounds__(256) void k_vpool(const float* __restrict__ numH,
                                               const float* __restrict__ denH,
                                               float* __restrict__ mom) {
    const int i = blockIdx.x * 256 + threadIdx.x;
    const int hw = i % HWn;
    const int bc = i / HWn;
    const int w = hw % Wn, h = hw / Wn;

    float den = 0.f;
    float n[Kn];
#pragma unroll
    for (int k = 0; k < Kn; ++k) n[k] = 0.f;

#pragma unroll
    for (int dy = -3; dy <= 3; ++dy) {
        int hh = h + dy;
        if (hh < 0 || hh >= Hn) continue;
        int px = hh * Wn + w;
        den += denH[(size_t)bc * HWn + px];
#pragma unroll
        for (int k = 0; k < Kn; ++k)
            n[k] += numH[(size_t)(bc * Kn + k) * HWn + px];
    }
    float dA = den * (1.0f / 49.0f);
    float inv = 1.0f / (dA + EPSF);
    float vm = (dA > MINM) ? 1.0f : 0.0f;
    float r[Kn];
#pragma unroll
    for (int k = 0; k < Kn; ++k) r[k] = n[k] * (1.0f / 49.0f) * inv * vm; // pre-masked

    // block-reduce 66 moments
    __shared__ float red[4][NMOM];
    const int lane = threadIdx.x & 63, wv = threadIdx.x >> 6;
    {
        float x = wred64(vm);
        if (lane == 0) red[wv][0] = x;
    }
#pragma unroll
    for (int k = 0; k < Kn; ++k) {
        float x = wred64(r[k]);
        if (lane == 0) red[wv][1 + k] = x;
    }
    int p = 11;
#pragma unroll
    for (int k = 0; k < Kn; ++k) {
#pragma unroll
        for (int l = 0; l <= k; ++l, ++p) {
            float x = wred64(r[k] * r[l]); // vm^2 == vm, r pre-masked
            if (lane == 0) red[wv][p] = x;
        }
    }
    __syncthreads();
    for (int t = threadIdx.x; t < NMOM; t += 256)
        atomicAdd(&mom[bc * NMOM + t],
                  red[0][t] + red[1][t] + red[2][t] + red[3][t]);
}

// ---------------------------------------------------------------------------
// K5: finalize from raw moments: M[kl] = S_kl - S_k S_l / Vf, loss, scalar
__global__ __launch_bounds__(64) void k_final(const float* __restrict__ mom,
                                              const int* __restrict__ cnt,
                                              float* __restrict__ out) {
    const int bc = threadIdx.x; // 0..63
    float mo[NMOM];
#pragma unroll
    for (int t = 0; t < NMOM; ++t) mo[t] = mom[bc * NMOM + t];
    const float V = mo[0];
    const float Vf = fmaxf(V, 1.0f);
    float Sk[Kn];
#pragma unroll
    for (int k = 0; k < Kn; ++k) Sk[k] = mo[1 + k];

    float M[55];
    {
        int p = 0;
#pragma unroll
        for (int k = 0; k < Kn; ++k)
#pragma unroll
            for (int l = 0; l <= k; ++l, ++p)
                M[p] = mo[11 + p] - Sk[k] * Sk[l] / Vf;
    }
    float nrm[Kn];
#pragma unroll
    for (int k = 0; k < Kn; ++k)
        nrm[k] = sqrtf(fmaxf(M[k * (k + 1) / 2 + k], 0.0f));
    float loss = 0.f;
    {
        int p = 0;
#pragma unroll
        for (int k = 0; k < Kn; ++k) {
#pragma unroll
            for (int l = 0; l <= k; ++l, ++p) {
                if (l == k) continue;
                float g = M[p] / ((nrm[k] + EPSF) * (nrm[l] + EPSF)) / Vf;
                loss += 2.0f * g * g;
            }
        }
    }
    loss *= 1.0f / (float)(Kn * (Kn - 1));
    bool act = (cnt[bc] >= 1) && (V >= 2.0f);
    float sl = act ? loss : 0.f;
    float sa = act ? 1.f : 0.f;
#pragma unroll
    for (int o = 4; o > 0; o >>= 1) {
        sl += __shfl_down(sl, o, 8);
        sa += __shfl_down(sa, o, 8);
    }
    __shared__ float pimg[Bn];
    if ((bc & 7) == 0) pimg[bc >> 3] = sl / fmaxf(sa, 1.0f);
    __syncthreads();
    if (bc == 0) {
        float tot = 0.f;
#pragma unroll
        for (int b = 0; b < Bn; ++b) tot += pimg[b];
        out[0] = tot / (float)Bn;
    }
}

// ---------------------------------------------------------------------------
extern "C" void kernel_launch(void* const* d_in, const int* in_sizes, int n_in,
                              void* d_out, int out_size, void* d_ws, size_t ws_size,
                              hipStream_t stream) {
    const float* F  = (const float*)d_in[0];
    const float* P  = (const float*)d_in[1];
    const int* mask = (const int*)d_in[2];
    float* ws = (float*)d_ws;
    float* out = (float*)d_out;

    hipMemsetAsync(ws + oMom, 0, (oEnd - oMom) * sizeof(float), stream);

    k_protonorm<<<CKn, 64, 0, stream>>>(P, ws + oPnT);
    k_sim<<<dim3(NPIX / 256, NCHUNK), 256, 0, stream>>>(F, ws + oPnT, mask, ws + oPart);
    k_simred<<<NPIX / 256, 256, 0, stream>>>(ws + oPart, mask, ws + oS, (int*)(ws + oCnt));
    k_hpool<<<Bn * Cn * 5 * HWn / 256, 256, 0, stream>>>(mask, ws + oS, ws + oNumH, ws + oDenH);
    k_vpool<<<Bn * Cn * HWn / 256, 256, 0, stream>>>(ws + oNumH, ws + oDenH, ws + oMom);
    k_final<<<1, 64, 0, stream>>>(ws + oMom, (const int*)(ws + oCnt), out);
}

// Round 4
// 286.003 us; speedup vs baseline: 1.4769x; 1.0781x over previous
//
#include <hip/hip_runtime.h>
#include <cstdint>
#include <cstddef>

namespace {
constexpr int Bn = 8, Dn = 512, Hn = 96, Wn = 96, HWn = Hn * Wn; // 9216
constexpr int Cn = 8, Kn = 10, CKn = Cn * Kn;                    // 80
constexpr int NPIX = Bn * HWn;                                   // 73728
constexpr int NCHUNK = 4, DCH = Dn / NCHUNK;                     // 4 x 128
constexpr int NMOM = 66;                                         // vm, 10 S_k, 55 S_kl
constexpr float EPSF = 1e-8f;
constexpr float MINM = 0.05f;

// workspace layout (floats)
constexpr size_t oPnT  = 0;                                    // [D][CK] 40960
constexpr size_t oS    = oPnT + (size_t)Dn * CKn;              // [B][K][HW] 737280
constexpr size_t oNumH = oS + (size_t)Bn * Kn * HWn;           // [BC][K][HW] 5898240
constexpr size_t oPart = oNumH;                                // alias: [chunk][11][NPIX] (consumed before numH written)
constexpr size_t oDenH = oNumH + (size_t)Bn * Cn * Kn * HWn;   // [BC][HW] 589824
constexpr size_t oMom  = oDenH + (size_t)Bn * Cn * HWn;        // [BC][66] 4224 (zeroed)
constexpr size_t oCnt  = oMom + 64 * NMOM;                     // [BC] int 64  (zeroed)
constexpr size_t oEnd  = oCnt + 64;
} // namespace

__device__ __forceinline__ float wred64(float v) {
#pragma unroll
    for (int o = 32; o > 0; o >>= 1) v += __shfl_down(v, o, 64);
    return v;
}

// ---------------------------------------------------------------------------
// K0: normalize prototypes, store transposed PnT[d][ck]
__global__ __launch_bounds__(64) void k_protonorm(const float* __restrict__ P,
                                                  float* __restrict__ PnT) {
    int ck = blockIdx.x, lane = threadIdx.x;
    float v[8]; float ss = 0.f;
#pragma unroll
    for (int j = 0; j < 8; ++j) { v[j] = P[ck * Dn + lane + 64 * j]; ss += v[j] * v[j]; }
    ss = wred64(ss);
    ss = __shfl(ss, 0, 64);
    float inv = 1.0f / fmaxf(sqrtf(ss), 1e-12f);
#pragma unroll
    for (int j = 0; j < 8; ++j)
        PnT[(size_t)(lane + 64 * j) * CKn + ck] = v[j] * inv;
}

// ---------------------------------------------------------------------------
// K1: split-D partial sims. grid (288 pixel-blocks, 4 d-chunks).
__global__ __launch_bounds__(256) void k_sim(const float* __restrict__ F,
                                             const float* __restrict__ PnT,
                                             const int* __restrict__ mask,
                                             float* __restrict__ part) {
    __shared__ float pch[64 * 96]; // [dd][c*12+k], padded, 24.6 KB
    const int tid = threadIdx.x;
    const int pix = blockIdx.x * 256 + tid;
    const int chunk = blockIdx.y;
    const int b = pix / HWn, hw = pix % HWn;

    const int m = mask[pix];
    const int cc = m > 0 ? m - 1 : 0;

    float acc[Kn]; float ss = 0.f;
#pragma unroll
    for (int k = 0; k < Kn; ++k) acc[k] = 0.f;

    for (int p = 0; p < DCH / 64; ++p) {
        const int dbase = chunk * DCH + p * 64;
        __syncthreads();
        for (int i = tid; i < 64 * CKn; i += 256) {
            int dd = i / CKn, ck = i % CKn;
            int c = ck / Kn, kk = ck % Kn;
            pch[dd * 96 + c * 12 + kk] = PnT[(size_t)(dbase + dd) * CKn + ck];
        }
        __syncthreads();
#pragma unroll 4
        for (int dd = 0; dd < 64; ++dd) {
            float f = F[(size_t)(b * Dn + dbase + dd) * HWn + hw];
            ss += f * f;
            const float4* p4 = (const float4*)&pch[dd * 96 + cc * 12];
            float4 pa = p4[0], pb = p4[1];
            float2 pc = *(const float2*)&pch[dd * 96 + cc * 12 + 8];
            acc[0] += f * pa.x; acc[1] += f * pa.y; acc[2] += f * pa.z; acc[3] += f * pa.w;
            acc[4] += f * pb.x; acc[5] += f * pb.y; acc[6] += f * pb.z; acc[7] += f * pb.w;
            acc[8] += f * pc.x; acc[9] += f * pc.y;
        }
    }
#pragma unroll
    for (int k = 0; k < Kn; ++k)
        part[(size_t)(chunk * 11 + k) * NPIX + pix] = acc[k];
    part[(size_t)(chunk * 11 + 10) * NPIX + pix] = ss;
}

// ---------------------------------------------------------------------------
// K2: reduce chunks, normalize, write S[b][k][hw]; class histogram.
__global__ __launch_bounds__(256) void k_simred(const float* __restrict__ part,
                                                const int* __restrict__ mask,
                                                float* __restrict__ S,
                                                int* __restrict__ cnt) {
    __shared__ int hist[Cn];
    const int tid = threadIdx.x;
    const int pix = blockIdx.x * 256 + tid;
    if (tid < Cn) hist[tid] = 0;
    __syncthreads();

    float acc[Kn]; float ss = 0.f;
#pragma unroll
    for (int k = 0; k < Kn; ++k) acc[k] = 0.f;
#pragma unroll
    for (int ch = 0; ch < NCHUNK; ++ch) {
#pragma unroll
        for (int k = 0; k < Kn; ++k)
            acc[k] += part[(size_t)(ch * 11 + k) * NPIX + pix];
        ss += part[(size_t)(ch * 11 + 10) * NPIX + pix];
    }
    float inv = 1.0f / fmaxf(sqrtf(ss), 1e-12f);
    const int b = pix / HWn, hw = pix % HWn;
#pragma unroll
    for (int k = 0; k < Kn; ++k)
        S[(size_t)(b * Kn + k) * HWn + hw] = acc[k] * inv;

    const int m = mask[pix];
    if (m > 0) atomicAdd(&hist[m - 1], 1);
    __syncthreads();
    if (tid < Cn) atomicAdd(&cnt[(pix / HWn) * Cn + tid], hist[tid]);
}

// ---------------------------------------------------------------------------
// K3: horizontal 7-pool; thread per (bc, k-pair, h, w-group-of-4).
// Columns w0-3..w0+6 are loaded once and added into the (up to 4) outputs
// whose window covers them — ascending-column order, bit-identical sums.
__global__ __launch_bounds__(256) void k_hpool(const int* __restrict__ mask,
                                               const float* __restrict__ S,
                                               float* __restrict__ numH,
                                               float* __restrict__ denH) {
    const int t = blockIdx.x * 256 + threadIdx.x; // ((bc*5+k2)*96+h)*24+wg
    const int wg = t % 24;
    int r = t / 24;
    const int h = r % Hn; r /= Hn;
    const int k2 = r % 5;
    const int bc = r / 5;
    const int c = bc & 7, b = bc >> 3;
    const int k0 = 2 * k2;
    const int w0 = wg * 4;
    const int rowb = b * HWn + h * Wn;
    const float* S0 = &S[(size_t)(b * Kn + k0) * HWn + h * Wn];
    const float* S1 = &S[(size_t)(b * Kn + k0 + 1) * HWn + h * Wn];

    float a0[4] = {0.f, 0.f, 0.f, 0.f};
    float a1[4] = {0.f, 0.f, 0.f, 0.f};
    float dn[4] = {0.f, 0.f, 0.f, 0.f};

#pragma unroll
    for (int dc = -3; dc <= 6; ++dc) {
        int ww = w0 + dc;
        if (ww < 0 || ww >= Wn) continue;
        float hv = (mask[rowb + ww] == c + 1) ? 1.0f : 0.0f;
        float s0 = S0[ww] * hv;
        float s1 = S1[ww] * hv;
        const int olo = dc - 3 > 0 ? dc - 3 : 0;
        const int ohi = dc + 3 < 3 ? dc + 3 : 3;
#pragma unroll
        for (int o = 0; o < 4; ++o) {
            if (o < olo || o > ohi) continue;
            a0[o] += s0; a1[o] += s1; dn[o] += hv;
        }
    }
    float4* n0 = (float4*)&numH[(size_t)(bc * Kn + k0) * HWn + h * Wn + w0];
    float4* n1 = (float4*)&numH[(size_t)(bc * Kn + k0 + 1) * HWn + h * Wn + w0];
    *n0 = make_float4(a0[0], a0[1], a0[2], a0[3]);
    *n1 = make_float4(a1[0], a1[1], a1[2], a1[3]);
    if (k2 == 0)
        *(float4*)&denH[(size_t)bc * HWn + h * Wn + w0] =
            make_float4(dn[0], dn[1], dn[2], dn[3]);
}

// ---------------------------------------------------------------------------
// K4: vertical 7-pool, 4 outputs/thread along H (rows h0-3..h0+6 loaded once,
// shared across the 4 overlapping windows); thread-local raw moments, one
// 66-way block reduction, atomics into mom[bc][66].
__global__ __launch_bounds__(256) void k_vpool(const float* __restrict__ numH,
                                               const float* __restrict__ denH,
                                               float* __restrict__ mom) {
    const int t = blockIdx.x * 256 + threadIdx.x; // (bc*24+hg)*96+w
    const int w = t % Wn;
    int r = t / Wn;
    const int hg = r % 24;
    const int bc = r / 24;
    const int h0 = hg * 4;

    float nacc[4][Kn];
    float dacc[4] = {0.f, 0.f, 0.f, 0.f};
#pragma unroll
    for (int o = 0; o < 4; ++o)
#pragma unroll
        for (int k = 0; k < Kn; ++k) nacc[o][k] = 0.f;

#pragma unroll
    for (int dr = -3; dr <= 6; ++dr) {
        int hh = h0 + dr;
        if (hh < 0 || hh >= Hn) continue;
        const int olo = dr - 3 > 0 ? dr - 3 : 0;
        const int ohi = dr + 3 < 3 ? dr + 3 : 3;
        float dv = denH[(size_t)bc * HWn + hh * Wn + w];
#pragma unroll
        for (int o = 0; o < 4; ++o) {
            if (o < olo || o > ohi) continue;
            dacc[o] += dv;
        }
#pragma unroll
        for (int k = 0; k < Kn; ++k) {
            float nv = numH[(size_t)(bc * Kn + k) * HWn + hh * Wn + w];
#pragma unroll
            for (int o = 0; o < 4; ++o) {
                if (o < olo || o > ohi) continue;
                nacc[o][k] += nv;
            }
        }
    }

    // thread-local moments over the 4 output pixels
    float m[NMOM];
#pragma unroll
    for (int i = 0; i < NMOM; ++i) m[i] = 0.f;
#pragma unroll
    for (int o = 0; o < 4; ++o) {
        float dA = dacc[o] * (1.0f / 49.0f);
        float inv = 1.0f / (dA + EPSF);
        float vm = (dA > MINM) ? 1.0f : 0.0f;
        float rr[Kn];
#pragma unroll
        for (int k = 0; k < Kn; ++k)
            rr[k] = nacc[o][k] * (1.0f / 49.0f) * inv * vm; // pre-masked
        m[0] += vm;
#pragma unroll
        for (int k = 0; k < Kn; ++k) m[1 + k] += rr[k];
        int p = 11;
#pragma unroll
        for (int k = 0; k < Kn; ++k)
#pragma unroll
            for (int l = 0; l <= k; ++l, ++p) m[p] += rr[k] * rr[l];
    }

    // block-reduce 66 moments
    __shared__ float red[4][NMOM];
    const int lane = threadIdx.x & 63, wv = threadIdx.x >> 6;
#pragma unroll
    for (int i = 0; i < NMOM; ++i) {
        float x = wred64(m[i]);
        if (lane == 0) red[wv][i] = x;
    }
    __syncthreads();
    for (int i = threadIdx.x; i < NMOM; i += 256)
        atomicAdd(&mom[bc * NMOM + i],
                  red[0][i] + red[1][i] + red[2][i] + red[3][i]);
}

// ---------------------------------------------------------------------------
// K5: finalize from raw moments: M[kl] = S_kl - S_k S_l / Vf, loss, scalar
__global__ __launch_bounds__(64) void k_final(const float* __restrict__ mom,
                                              const int* __restrict__ cnt,
                                              float* __restrict__ out) {
    const int bc = threadIdx.x; // 0..63
    float mo[NMOM];
#pragma unroll
    for (int i = 0; i < NMOM; ++i) mo[i] = mom[bc * NMOM + i];
    const float V = mo[0];
    const float Vf = fmaxf(V, 1.0f);
    float Sk[Kn];
#pragma unroll
    for (int k = 0; k < Kn; ++k) Sk[k] = mo[1 + k];

    float M[55];
    {
        int p = 0;
#pragma unroll
        for (int k = 0; k < Kn; ++k)
#pragma unroll
            for (int l = 0; l <= k; ++l, ++p)
                M[p] = mo[11 + p] - Sk[k] * Sk[l] / Vf;
    }
    float nrm[Kn];
#pragma unroll
    for (int k = 0; k < Kn; ++k)
        nrm[k] = sqrtf(fmaxf(M[k * (k + 1) / 2 + k], 0.0f));
    float loss = 0.f;
    {
        int p = 0;
#pragma unroll
        for (int k = 0; k < Kn; ++k) {
#pragma unroll
            for (int l = 0; l <= k; ++l, ++p) {
                if (l == k) continue;
                float g = M[p] / ((nrm[k] + EPSF) * (nrm[l] + EPSF)) / Vf;
                loss += 2.0f * g * g;
            }
        }
    }
    loss *= 1.0f / (float)(Kn * (Kn - 1));
    bool act = (cnt[bc] >= 1) && (V >= 2.0f);
    float sl = act ? loss : 0.f;
    float sa = act ? 1.f : 0.f;
#pragma unroll
    for (int o = 4; o > 0; o >>= 1) {
        sl += __shfl_down(sl, o, 8);
        sa += __shfl_down(sa, o, 8);
    }
    __shared__ float pimg[Bn];
    if ((bc & 7) == 0) pimg[bc >> 3] = sl / fmaxf(sa, 1.0f);
    __syncthreads();
    if (bc == 0) {
        float tot = 0.f;
#pragma unroll
        for (int b = 0; b < Bn; ++b) tot += pimg[b];
        out[0] = tot / (float)Bn;
    }
}

// ---------------------------------------------------------------------------
extern "C" void kernel_launch(void* const* d_in, const int* in_sizes, int n_in,
                              void* d_out, int out_size, void* d_ws, size_t ws_size,
                              hipStream_t stream) {
    const float* F  = (const float*)d_in[0];
    const float* P  = (const float*)d_in[1];
    const int* mask = (const int*)d_in[2];
    float* ws = (float*)d_ws;
    float* out = (float*)d_out;

    hipMemsetAsync(ws + oMom, 0, (oEnd - oMom) * sizeof(float), stream);

    k_protonorm<<<CKn, 64, 0, stream>>>(P, ws + oPnT);
    k_sim<<<dim3(NPIX / 256, NCHUNK), 256, 0, stream>>>(F, ws + oPnT, mask, ws + oPart);
    k_simred<<<NPIX / 256, 256, 0, stream>>>(ws + oPart, mask, ws + oS, (int*)(ws + oCnt));
    k_hpool<<<Bn * Cn * 5 * Hn * 24 / 256, 256, 0, stream>>>(mask, ws + oS,
                                                             ws + oNumH, ws + oDenH);
    k_vpool<<<Bn * Cn * 24 * Wn / 256, 256, 0, stream>>>(ws + oNumH, ws + oDenH, ws + oMom);
    k_final<<<1, 64, 0, stream>>>(ws + oMom, (const int*)(ws + oCnt), out);
}